// Round 11
// baseline (363.037 us; speedup 1.0000x reference)
//
#include <hip/hip_runtime.h>

typedef __attribute__((ext_vector_type(8))) short bf16x8;
typedef __attribute__((ext_vector_type(8))) short short8;
typedef __attribute__((ext_vector_type(4))) float f32x4;

#define SL 2048
#define DM 768
#define NCH 32
#define MSPEC 24576   /* 32*768 */
#define MTOT  26880   /* 24576 + 3*768 */

/* ---- gemm2 8-phase geometry ---- */
#define SPLITK 10
#define KSLICE 2688   /* 26880/10 = 42 K-tiles of 64 (even) */
#define NT2 42
#define NITER2 21     /* 2 K-tiles per iteration */

/* workspace layout */
#define WS_U      0ULL
#define WS_TMAT   110100480ULL          /* 513 blocks of 128x128 bf16 (last = zeros) */
#define WS_XT     126910464ULL
#define WS_MCAT   130056192ULL
#define WS_PART   171343872ULL          /* SPLITK x 2048 x 768 f32 partials */
#define WS_NEED   234258432ULL

/* fused prep grid partition */
#define NB_M   5040                     /* 420 x 12 */
#define NB_T   4104                     /* 513*16384/8/256 */
#define NB_AR  768                      /* 2048*96/256 */
#define NB_XT  384                      /* 12 x 32 */
#define NB_ALL (NB_M + NB_T + NB_AR + NB_XT)

__device__ __forceinline__ short f2bf(float f) {
  unsigned u = __builtin_bit_cast(unsigned, f);
  u = (u + 0x7FFFu + ((u >> 16) & 1u)) >> 16;
  return (short)u;
}

// async global->LDS, 16B per lane. LDS dest must be wave-uniform base + lane*16.
__device__ __forceinline__ void gload16(const short* g, short* l) {
  __builtin_amdgcn_global_load_lds(
      (const __attribute__((address_space(1))) void*)g,
      (__attribute__((address_space(3))) void*)l, 16, 0, 0);
}

// ---------------- prep kernels ----------------

__global__ __launch_bounds__(256) void k_zero(float4* out) {
  out[blockIdx.x * 256 + threadIdx.x] = float4{0.f, 0.f, 0.f, 0.f};
}

// One fused launch for all independent prep work; branch by blockIdx range.
__global__ __launch_bounds__(256) void k_prep_all(const float* __restrict__ x,
                                                  const float* __restrict__ phi,
                                                  const float* __restrict__ sigma,
                                                  const float* __restrict__ Mp,
                                                  const float* __restrict__ Mm,
                                                  const float* __restrict__ Mu,
                                                  short* __restrict__ xT,
                                                  short* __restrict__ U,
                                                  short* __restrict__ Tmat,
                                                  short* __restrict__ McatT) {
  __shared__ short tile[64][65];
  const int b = blockIdx.x;
  const int t = threadIdx.x;

  if (b < NB_M) {
    // McatT[o][m] (768 x 26880): m<24576 -> sigma^(1/4)-scaled Mp/Mm; else Mu
    const int m0 = (b % 420) * 64, o0 = (b / 420) * 64;
#pragma unroll
    for (int rr = 0; rr < 16; ++rr) {
      int ml = rr * 4 + (t >> 6), ol = t & 63;
      int m = m0 + ml, o = o0 + ol;
      float v;
      if (m < MSPEC) {
        int c = m / DM, d = m - c * DM;
        int k = c & 15;
        float s4 = sqrtf(sqrtf(sigma[k]));
        if (c < 16) v = Mp[((size_t)c * DM + d) * DM + o] * s4;
        else        v = Mm[((size_t)(c - 16) * DM + d) * DM + o] * s4;
      } else {
        int mm = m - MSPEC;
        int i = mm / DM, d = mm - i * DM;
        v = Mu[((size_t)i * DM + d) * DM + o];
      }
      tile[ml][ol] = f2bf(v);
    }
    __syncthreads();
#pragma unroll
    for (int rr = 0; rr < 16; ++rr) {
      int ol = rr * 4 + (t >> 6), ml = t & 63;
      McatT[(size_t)(o0 + ol) * MTOT + m0 + ml] = tile[ml][ol];
    }
    return;
  }
  if (b < NB_M + NB_T) {
    // Tmat[c][dlag][a][b8] = f_c[dlag*128 + a - b]; block 512 = zeros; 8 elems/thread
    int idx = ((b - NB_M) * 256 + t) * 8;
    int c = idx >> 18;
    short8 v = {0, 0, 0, 0, 0, 0, 0, 0};
    if (c < 32) {
      int b0 = idx & 127, a = (idx >> 7) & 127, dlag = (idx >> 14) & 15;
      int j0 = dlag * 128 + a - b0;
#pragma unroll
      for (int e = 0; e < 8; ++e) {
        int j = j0 - e;
        if (j >= 0) {
          float p = phi[j * 16 + (c & 15)];
          if (c >= 16 && (j & 1)) p = -p;
          v[e] = f2bf(p);
        }
      }
    }
    *reinterpret_cast<short8*>(&Tmat[idx]) = v;
    return;
  }
  if (b < NB_M + NB_T + NB_AR) {
    // AR columns of U: U[l][24576 + i*768 + d] = x[l-i][d]; 8 d-values/thread
    int tid = (b - NB_M - NB_T) * 256 + t;   // over 2048*96
    int l = tid / 96, d0 = (tid - l * 96) * 8;
#pragma unroll
    for (int i = 0; i < 3; ++i) {
      short8 v = {0, 0, 0, 0, 0, 0, 0, 0};
      if (l >= i) {
        const float* src = &x[(size_t)(l - i) * DM + d0];
#pragma unroll
        for (int e = 0; e < 8; ++e) v[e] = f2bf(src[e]);
      }
      *reinterpret_cast<short8*>(&U[(size_t)l * MTOT + MSPEC + i * DM + d0]) = v;
    }
    return;
  }
  {
    // xT[d][l] = bf16(x[l][d])   (768 x 2048), LDS tiled transpose
    const int bb = b - NB_M - NB_T - NB_AR;
    const int d0 = (bb % 12) * 64, l0 = (bb / 12) * 64;
#pragma unroll
    for (int rr = 0; rr < 16; ++rr) {
      int ll = rr * 4 + (t >> 6), dl = t & 63;
      tile[ll][dl] = f2bf(x[(size_t)(l0 + ll) * DM + d0 + dl]);
    }
    __syncthreads();
#pragma unroll
    for (int rr = 0; rr < 16; ++rr) {
      int dl = rr * 4 + (t >> 6), ll = t & 63;
      xT[(size_t)(d0 + dl) * SL + l0 + ll] = tile[ll][dl];
    }
  }
}

// ---------------- shared 8-phase machinery ----------------
// LDS panels [buf][ks][rowhalf][128*32] for A and B; chunk-XOR swizzle staged via
// pre-swizzled global source (cswz) + matching read offset (foff). 2 gloads/stage-unit.
// vmcnt(6) only at ph0/ph4 (3 units = 6 loads stay in flight); last iter ph4 drains 0.
// One barrier per same-buffer phase (write-after-read hazard is covered by the
// previous phase's lgkmcnt(0)+barrier); two barriers only on the 2 buffer-crossing
// phases. MFMA<-ds_read ordering is compiler-tracked (plain loads); the closing
// lgkmcnt(0) (free by then) protects reads before the phase-closing barrier.

#define LDSREADS(BUF, KS, MQ)                                                   \
    _Pragma("unroll")                                                           \
    for (int q_ = 0; q_ < 4; ++q_)                                              \
      af_[q_] = *reinterpret_cast<const bf16x8*>(                               \
          &As[BUF][KS][wm1][((MQ) * 64 + q_ * 16 + lrow) * 32 + foff]);         \
    if ((MQ) == 0) {                                                            \
      _Pragma("unroll")                                                         \
      for (int i_ = 0; i_ < 4; ++i_)                                            \
        bf_[i_] = *reinterpret_cast<const bf16x8*>(                             \
            &Bs[BUF][KS][hB][(rB0 + i_ * 16 + lrow) * 32 + foff]);              \
    }

#define DOMFMA(MQ)                                                              \
    _Pragma("unroll")                                                           \
    for (int q_ = 0; q_ < 4; ++q_)                                              \
      _Pragma("unroll")                                                         \
      for (int i_ = 0; i_ < 4; ++i_)                                            \
        acc[(MQ) * 4 + q_][i_] = __builtin_amdgcn_mfma_f32_16x16x32_bf16(       \
            af_[q_], bf_[i_], acc[(MQ) * 4 + q_][i_], 0, 0, 0)

// VMODE: 0 = same-buffer phase: reads+stage+MFMA, single closing barrier
//        1 = buffer-crossing: vmcnt(6); stage; barrier; reads; MFMA; barrier
//        2 = as 1 but vmcnt(0) on the last iteration (tail stages skipped)
#define PHASE(BUF, KS, MQ, VMODE, STG) do {                                     \
    bf16x8 af_[4];                                                              \
    if ((VMODE) == 1) asm volatile("s_waitcnt vmcnt(6)" ::: "memory");          \
    if ((VMODE) == 2) {                                                         \
      if (j < nIterM1) asm volatile("s_waitcnt vmcnt(6)" ::: "memory");         \
      else             asm volatile("s_waitcnt vmcnt(0)" ::: "memory");         \
    }                                                                           \
    if ((VMODE) == 0) { LDSREADS(BUF, KS, MQ) }                                 \
    STG;                                                                        \
    if ((VMODE) != 0) {                                                         \
      __builtin_amdgcn_s_barrier();                                             \
      asm volatile("" ::: "memory");                                            \
      LDSREADS(BUF, KS, MQ)                                                     \
    }                                                                           \
    __builtin_amdgcn_s_setprio(1);                                              \
    DOMFMA(MQ);                                                                 \
    __builtin_amdgcn_s_setprio(0);                                              \
    asm volatile("s_waitcnt lgkmcnt(0)" ::: "memory");                          \
    __builtin_amdgcn_s_barrier();                                               \
  } while (0)

// ---------------- GEMM 1: block-Toeplitz conv, 256x256 tile, 8-phase ----------------
// grid 768 = 8 XCD-pinned x {4 channels x 3 coltiles x 8 rowtiles}; big-K (rt=7) first.
// A[row][k] = phi_c[l - k]: Toeplitz staging from Tmat; dlag=-1 -> zero block 512.
// K per block = 256*(rt+1); NITER = 2*(rt+1).

#define STA1(SBUF, SKS, SKT) do { int kt_ = (SKT); if (kt_ < nT) {              \
    int kch_ = kt_ * 64 + (SKS) * 32;                                           \
    int kb_ = kch_ >> 7, bo_ = kch_ & 127;                                      \
    int dl_ = 2 * rt - kb_;                                                     \
    const short* g0_ = (dl_ >= 0) ? (Tc + ((size_t)dl_ << 14) + bo_)            \
                                  : (Tz + bo_);                                 \
    const short* g1_ = Tc + ((size_t)(dl_ + 1) << 14) + bo_;                    \
    gload16(g0_, &As[SBUF][SKS][0][t8]);                                        \
    gload16(g1_, &As[SBUF][SKS][1][t8]); } } while (0)

#define STB1(SBUF, SKS, SKT) do { int kt_ = (SKT); if (kt_ < nT) {              \
    const short* g_ = Bb + kt_ * 64 + (SKS) * 32;                               \
    gload16(g_, &Bs[SBUF][SKS][0][t8]);                                         \
    gload16(g_ + (size_t)128 * SL, &Bs[SBUF][SKS][1][t8]); } } while (0)

__global__ __launch_bounds__(512, 2) void k_gemm1_8p(const short* __restrict__ Tmat,
                                                     const short* __restrict__ xT,
                                                     short* __restrict__ U) {
  __shared__ __align__(16) short As[2][2][2][4096];
  __shared__ __align__(16) short Bs[2][2][2][4096];
  const int bid = blockIdx.x;
  const int xcd = bid & 7;
  const int slot = bid >> 3;                 // 0..95
  const int c = xcd * 4 + (slot & 3);        // 4 channels per XCD (Tmat L2-resident)
  const int q = slot >> 2;                   // 0..23
  const int ct = q % 3;
  const int rt = 7 - q / 3;                  // big K first
  const int nT = 4 * (rt + 1);
  const int nIter = 2 * (rt + 1);
  const int nIterM1 = nIter - 1;
  const int t = threadIdx.x;
  const int lane = t & 63, wave = t >> 6;
  const int wm1 = wave >> 2;
  const int hB = (wave & 3) >> 1;
  const int rB0 = (wave & 1) * 64;
  const int lrow = lane & 15, quad = lane >> 4;
  const int foff = (quad ^ ((lrow >> 1) & 3)) << 3;
  const int r = t >> 2;
  const int cswz = ((t & 3) ^ ((r >> 1) & 3)) << 3;
  const int t8 = t * 8;

  const short* Tc = Tmat + ((size_t)(c * 16) << 14) + r * 128 + cswz;
  const short* Tz = Tmat + ((size_t)512 << 14) + r * 128 + cswz;
  const short* Bb = xT + (size_t)(ct * 256 + r) * SL + cswz;

  f32x4 acc[8][4] = {};

  STB1(0, 0, 0); STA1(0, 0, 0); STB1(0, 1, 0); STA1(0, 1, 0);
  STB1(1, 0, 1); STA1(1, 0, 1); STB1(1, 1, 1);

  for (int j = 0; j < nIter; ++j) {
    bf16x8 bf_[4];
    PHASE(0, 0, 0, 1, STA1(1, 1, 2 * j + 1));
    PHASE(0, 0, 1, 0, STB1(0, 0, 2 * j + 2));
    PHASE(0, 1, 0, 0, STA1(0, 0, 2 * j + 2));
    PHASE(0, 1, 1, 0, STB1(0, 1, 2 * j + 2));
    PHASE(1, 0, 0, 2, STA1(0, 1, 2 * j + 2));
    PHASE(1, 0, 1, 0, STB1(1, 0, 2 * j + 3));
    PHASE(1, 1, 0, 0, STA1(1, 0, 2 * j + 3));
    PHASE(1, 1, 1, 0, STB1(1, 1, 2 * j + 3));
  }

  const int wm128 = (wave >> 2) * 128, wn64 = (wave & 3) * 64;
  const int l0 = rt * 256, colbase = c * DM + ct * 256;
#pragma unroll
  for (int im = 0; im < 8; ++im)
#pragma unroll
    for (int in = 0; in < 4; ++in)
#pragma unroll
      for (int r4 = 0; r4 < 4; ++r4) {
        int row = l0 + wm128 + im * 16 + quad * 4 + r4;
        int col = colbase + wn64 + in * 16 + lrow;
        U[(size_t)row * MTOT + col] = f2bf(acc[im][in][r4]);
      }
}

// ---------------- GEMM 2: 256x256 tile, 8-phase; partial-store epilogue ----------------
// grid 240 = 24 output tiles x SPLITK=10. If use_part: write f32 partials (reduced by
// k_reduce); else atomicAdd fallback (workspace too small).

#define STA2(SBUF, SKS, SKT) do { int kt_ = (SKT); if (kt_ < NT2) {             \
    const short* g_ = Abase + kt_ * 64 + (SKS) * 32;                            \
    gload16(g_, &As[SBUF][SKS][0][t8]);                                         \
    gload16(g_ + (size_t)128 * MTOT, &As[SBUF][SKS][1][t8]); } } while (0)

#define STB2(SBUF, SKS, SKT) do { int kt_ = (SKT); if (kt_ < NT2) {             \
    const short* g_ = Bbase + kt_ * 64 + (SKS) * 32;                            \
    gload16(g_, &Bs[SBUF][SKS][0][t8]);                                         \
    gload16(g_ + (size_t)128 * MTOT, &Bs[SBUF][SKS][1][t8]); } } while (0)

__global__ __launch_bounds__(512, 2) void k_gemm2_8p(const short* __restrict__ U,
                                                     const short* __restrict__ McatT,
                                                     float* __restrict__ out,
                                                     float* __restrict__ part,
                                                     int use_part) {
  __shared__ __align__(16) short As[2][2][2][4096];
  __shared__ __align__(16) short Bs[2][2][2][4096];
  const int bid = blockIdx.x;
  const int tile = bid % 24, kc = bid / 24;
  const int mt = tile & 7, nt_ = tile >> 3;
  const int m0 = mt * 256, o0 = nt_ * 256;
  const int kbase = kc * KSLICE;
  const int t = threadIdx.x;
  const int lane = t & 63, wave = t >> 6;
  const int wm1 = wave >> 2;
  const int hB = (wave & 3) >> 1;
  const int rB0 = (wave & 1) * 64;
  const int lrow = lane & 15, quad = lane >> 4;
  const int foff = (quad ^ ((lrow >> 1) & 3)) << 3;
  const int r = t >> 2;
  const int cswz = ((t & 3) ^ ((r >> 1) & 3)) << 3;
  const int t8 = t * 8;
  const int nIterM1 = NITER2 - 1;

  const short* Abase = U     + (size_t)(m0 + r) * MTOT + kbase + cswz;
  const short* Bbase = McatT + (size_t)(o0 + r) * MTOT + kbase + cswz;

  f32x4 acc[8][4] = {};

  STB2(0, 0, 0); STA2(0, 0, 0); STB2(0, 1, 0); STA2(0, 1, 0);
  STB2(1, 0, 1); STA2(1, 0, 1); STB2(1, 1, 1);

  for (int j = 0; j < NITER2; ++j) {
    bf16x8 bf_[4];
    PHASE(0, 0, 0, 1, STA2(1, 1, 2 * j + 1));
    PHASE(0, 0, 1, 0, STB2(0, 0, 2 * j + 2));
    PHASE(0, 1, 0, 0, STA2(0, 0, 2 * j + 2));
    PHASE(0, 1, 1, 0, STB2(0, 1, 2 * j + 2));
    PHASE(1, 0, 0, 2, STA2(0, 1, 2 * j + 2));
    PHASE(1, 0, 1, 0, STB2(1, 0, 2 * j + 3));
    PHASE(1, 1, 0, 0, STA2(1, 0, 2 * j + 3));
    PHASE(1, 1, 1, 0, STB2(1, 1, 2 * j + 3));
  }

  const int wm128 = (wave >> 2) * 128, wn64 = (wave & 3) * 64;
  if (use_part) {
    float* dst = part + (size_t)kc * (2048 * 768);
#pragma unroll
    for (int im = 0; im < 8; ++im)
#pragma unroll
      for (int in = 0; in < 4; ++in)
#pragma unroll
        for (int r4 = 0; r4 < 4; ++r4) {
          int row = m0 + wm128 + im * 16 + quad * 4 + r4;
          int col = o0 + wn64 + in * 16 + lrow;
          dst[(size_t)row * DM + col] = acc[im][in][r4];
        }
  } else {
#pragma unroll
    for (int im = 0; im < 8; ++im)
#pragma unroll
      for (int in = 0; in < 4; ++in)
#pragma unroll
        for (int r4 = 0; r4 < 4; ++r4) {
          int row = m0 + wm128 + im * 16 + quad * 4 + r4;
          int col = o0 + wn64 + in * 16 + lrow;
          atomicAdd(&out[(size_t)row * DM + col], acc[im][in][r4]);
        }
  }
}

// out = sum over SPLITK partials; one float4 per thread (393216 total)
__global__ __launch_bounds__(256) void k_reduce(const float4* __restrict__ part,
                                                float4* __restrict__ out) {
  int i = blockIdx.x * 256 + threadIdx.x;
  float4 s = part[i];
#pragma unroll
  for (int k = 1; k < SPLITK; ++k) {
    float4 v = part[(size_t)k * 393216 + i];
    s.x += v.x; s.y += v.y; s.z += v.z; s.w += v.w;
  }
  out[i] = s;
}

extern "C" void kernel_launch(void* const* d_in, const int* in_sizes, int n_in,
                              void* d_out, int out_size, void* d_ws, size_t ws_size,
                              hipStream_t stream) {
  (void)in_sizes; (void)n_in; (void)out_size;
  const float* x     = (const float*)d_in[0];
  const float* phi   = (const float*)d_in[1];
  const float* sigma = (const float*)d_in[2];
  const float* Mp    = (const float*)d_in[3];
  const float* Mm    = (const float*)d_in[4];
  const float* Mu    = (const float*)d_in[5];
  float* out = (float*)d_out;
  char* ws = (char*)d_ws;

  short* U     = (short*)(ws + WS_U);
  short* Tmat  = (short*)(ws + WS_TMAT);
  short* xT    = (short*)(ws + WS_XT);
  short* McatT = (short*)(ws + WS_MCAT);
  float* Wpart = (float*)(ws + WS_PART);
  const int use_part = ws_size >= WS_NEED ? 1 : 0;

  if (!use_part)
    k_zero<<<dim3(1536), dim3(256), 0, stream>>>((float4*)out);
  k_prep_all<<<dim3(NB_ALL), dim3(256), 0, stream>>>(x, phi, sigma, Mp, Mm, Mu,
                                                     xT, U, Tmat, McatT);
  k_gemm1_8p<<<dim3(768), dim3(512), 0, stream>>>(Tmat, xT, U);
  k_gemm2_8p<<<dim3(240), dim3(512), 0, stream>>>(U, McatT, out, Wpart, use_part);
  if (use_part)
    k_reduce<<<dim3(1536), dim3(256), 0, stream>>>((const float4*)Wpart, (float4*)out);
}

// Round 12
// 354.396 us; speedup vs baseline: 1.0244x; 1.0244x over previous
//
#include <hip/hip_runtime.h>

typedef __attribute__((ext_vector_type(8))) short bf16x8;
typedef __attribute__((ext_vector_type(8))) short short8;
typedef __attribute__((ext_vector_type(4))) short short4v;
typedef __attribute__((ext_vector_type(4))) float f32x4;

#define SL 2048
#define DM 768
#define NCH 32
#define MSPEC 24576   /* 32*768 */
#define MTOT  26880   /* 24576 + 3*768 */

/* ---- gemm2 8-phase geometry ---- */
#define SPLITK 10
#define KSLICE 2688   /* 26880/10 = 42 K-tiles of 64 (even) */
#define NT2 42
#define NITER2 21     /* 2 K-tiles per iteration */

/* workspace layout */
#define WS_U      0ULL
#define WS_TMAT   110100480ULL          /* 513 blocks of 128x128 bf16 (last = zeros) */
#define WS_XT     126910464ULL
#define WS_MCAT   130056192ULL
#define WS_PART   171343872ULL          /* SPLITK x 2048 x 768 f32 partials */
#define WS_NEED   234258432ULL

/* fused prep grid partition */
#define NB_M   5040                     /* 420 x 12 */
#define NB_T   4104                     /* 513*16384/8/256 */
#define NB_AR  768                      /* 2048*96/256 */
#define NB_XT  384                      /* 12 x 32 */
#define NB_ALL (NB_M + NB_T + NB_AR + NB_XT)

__device__ __forceinline__ short f2bf(float f) {
  unsigned u = __builtin_bit_cast(unsigned, f);
  u = (u + 0x7FFFu + ((u >> 16) & 1u)) >> 16;
  return (short)u;
}

// async global->LDS, 16B per lane. LDS dest must be wave-uniform base + lane*16.
__device__ __forceinline__ void gload16(const short* g, short* l) {
  __builtin_amdgcn_global_load_lds(
      (const __attribute__((address_space(1))) void*)g,
      (__attribute__((address_space(3))) void*)l, 16, 0, 0);
}

// ---------------- prep kernels ----------------

__global__ __launch_bounds__(256) void k_zero(float4* out) {
  out[blockIdx.x * 256 + threadIdx.x] = float4{0.f, 0.f, 0.f, 0.f};
}

// One fused launch for all independent prep work; branch by blockIdx range.
__global__ __launch_bounds__(256) void k_prep_all(const float* __restrict__ x,
                                                  const float* __restrict__ phi,
                                                  const float* __restrict__ sigma,
                                                  const float* __restrict__ Mp,
                                                  const float* __restrict__ Mm,
                                                  const float* __restrict__ Mu,
                                                  short* __restrict__ xT,
                                                  short* __restrict__ U,
                                                  short* __restrict__ Tmat,
                                                  short* __restrict__ McatT) {
  __shared__ short tile[64][65];
  const int b = blockIdx.x;
  const int t = threadIdx.x;

  if (b < NB_M) {
    // McatT[o][m] (768 x 26880): m<24576 -> sigma^(1/4)-scaled Mp/Mm; else Mu
    __shared__ float s4l[16];
    if (t < 16) s4l[t] = sqrtf(sqrtf(sigma[t]));
    __syncthreads();
    const int m0 = (b % 420) * 64, o0 = (b / 420) * 64;
#pragma unroll
    for (int rr = 0; rr < 16; ++rr) {
      int ml = rr * 4 + (t >> 6), ol = t & 63;
      int m = m0 + ml, o = o0 + ol;
      float v;
      if (m < MSPEC) {
        int c = m / DM, d = m - c * DM;
        float s4 = s4l[c & 15];
        if (c < 16) v = Mp[((size_t)c * DM + d) * DM + o] * s4;
        else        v = Mm[((size_t)(c - 16) * DM + d) * DM + o] * s4;
      } else {
        int mm = m - MSPEC;
        int i = mm / DM, d = mm - i * DM;
        v = Mu[((size_t)i * DM + d) * DM + o];
      }
      tile[ml][ol] = f2bf(v);
    }
    __syncthreads();
    // vectorized store: each lane writes 4 consecutive m (short4, 8B) at one o
#pragma unroll
    for (int i = 0; i < 4; ++i) {
      int u = i * 256 + t;                 // 1024 units = 64 o-rows x 16 m-groups
      int ol = u >> 4, ml0 = (u & 15) * 4;
      short4v v = {tile[ml0][ol], tile[ml0 + 1][ol],
                   tile[ml0 + 2][ol], tile[ml0 + 3][ol]};
      *reinterpret_cast<short4v*>(&McatT[(size_t)(o0 + ol) * MTOT + m0 + ml0]) = v;
    }
    return;
  }
  if (b < NB_M + NB_T) {
    // Tmat[c][dlag][a][b8] = f_c[dlag*128 + a - b]; block 512 = zeros; 8 elems/thread
    int idx = ((b - NB_M) * 256 + t) * 8;
    int c = idx >> 18;
    short8 v = {0, 0, 0, 0, 0, 0, 0, 0};
    if (c < 32) {
      int b0 = idx & 127, a = (idx >> 7) & 127, dlag = (idx >> 14) & 15;
      int j0 = dlag * 128 + a - b0;
#pragma unroll
      for (int e = 0; e < 8; ++e) {
        int j = j0 - e;
        if (j >= 0) {
          float p = phi[j * 16 + (c & 15)];
          if (c >= 16 && (j & 1)) p = -p;
          v[e] = f2bf(p);
        }
      }
    }
    *reinterpret_cast<short8*>(&Tmat[idx]) = v;
    return;
  }
  if (b < NB_M + NB_T + NB_AR) {
    // AR columns of U: U[l][24576 + i*768 + d] = x[l-i][d]; 8 d-values/thread
    int tid = (b - NB_M - NB_T) * 256 + t;   // over 2048*96
    int l = tid / 96, d0 = (tid - l * 96) * 8;
#pragma unroll
    for (int i = 0; i < 3; ++i) {
      short8 v = {0, 0, 0, 0, 0, 0, 0, 0};
      if (l >= i) {
        const float* src = &x[(size_t)(l - i) * DM + d0];
#pragma unroll
        for (int e = 0; e < 8; ++e) v[e] = f2bf(src[e]);
      }
      *reinterpret_cast<short8*>(&U[(size_t)l * MTOT + MSPEC + i * DM + d0]) = v;
    }
    return;
  }
  {
    // xT[d][l] = bf16(x[l][d])   (768 x 2048), LDS tiled transpose
    const int bb = b - NB_M - NB_T - NB_AR;
    const int d0 = (bb % 12) * 64, l0 = (bb / 12) * 64;
#pragma unroll
    for (int rr = 0; rr < 16; ++rr) {
      int ll = rr * 4 + (t >> 6), dl = t & 63;
      tile[ll][dl] = f2bf(x[(size_t)(l0 + ll) * DM + d0 + dl]);
    }
    __syncthreads();
#pragma unroll
    for (int rr = 0; rr < 16; ++rr) {
      int dl = rr * 4 + (t >> 6), ll = t & 63;
      xT[(size_t)(d0 + dl) * SL + l0 + ll] = tile[ll][dl];
    }
  }
}

// ---------------- shared 8-phase machinery ----------------
// LDS panels [buf][ks][rowhalf][128*32] for A and B; chunk-XOR swizzle staged via
// pre-swizzled global source (cswz) + matching read offset (foff). 2 gloads/stage-unit.
// vmcnt(6) only at ph0/ph4 (3 units = 6 loads stay in flight); last iter ph4 drains 0.
// One barrier per same-buffer phase (write-after-read hazard is covered by the
// previous phase's lgkmcnt(0)+barrier); two barriers only on the 2 buffer-crossing
// phases. MFMA<-ds_read ordering is compiler-tracked (plain loads); the closing
// lgkmcnt(0) (free by then) protects reads before the phase-closing barrier.

#define LDSREADS(BUF, KS, MQ)                                                   \
    _Pragma("unroll")                                                           \
    for (int q_ = 0; q_ < 4; ++q_)                                              \
      af_[q_] = *reinterpret_cast<const bf16x8*>(                               \
          &As[BUF][KS][wm1][((MQ) * 64 + q_ * 16 + lrow) * 32 + foff]);         \
    if ((MQ) == 0) {                                                            \
      _Pragma("unroll")                                                         \
      for (int i_ = 0; i_ < 4; ++i_)                                            \
        bf_[i_] = *reinterpret_cast<const bf16x8*>(                             \
            &Bs[BUF][KS][hB][(rB0 + i_ * 16 + lrow) * 32 + foff]);              \
    }

#define DOMFMA(MQ)                                                              \
    _Pragma("unroll")                                                           \
    for (int q_ = 0; q_ < 4; ++q_)                                              \
      _Pragma("unroll")                                                         \
      for (int i_ = 0; i_ < 4; ++i_)                                            \
        acc[(MQ) * 4 + q_][i_] = __builtin_amdgcn_mfma_f32_16x16x32_bf16(       \
            af_[q_], bf_[i_], acc[(MQ) * 4 + q_][i_], 0, 0, 0)

// VMODE: 0 = same-buffer phase: reads+stage+MFMA, single closing barrier
//        1 = buffer-crossing: vmcnt(6); stage; barrier; reads; MFMA; barrier
//        2 = as 1 but vmcnt(0) on the last iteration (tail stages skipped)
#define PHASE(BUF, KS, MQ, VMODE, STG) do {                                     \
    bf16x8 af_[4];                                                              \
    if ((VMODE) == 1) asm volatile("s_waitcnt vmcnt(6)" ::: "memory");          \
    if ((VMODE) == 2) {                                                         \
      if (j < nIterM1) asm volatile("s_waitcnt vmcnt(6)" ::: "memory");         \
      else             asm volatile("s_waitcnt vmcnt(0)" ::: "memory");         \
    }                                                                           \
    if ((VMODE) == 0) { LDSREADS(BUF, KS, MQ) }                                 \
    STG;                                                                        \
    if ((VMODE) != 0) {                                                         \
      __builtin_amdgcn_s_barrier();                                             \
      asm volatile("" ::: "memory");                                            \
      LDSREADS(BUF, KS, MQ)                                                     \
    }                                                                           \
    __builtin_amdgcn_s_setprio(1);                                              \
    DOMFMA(MQ);                                                                 \
    __builtin_amdgcn_s_setprio(0);                                              \
    asm volatile("s_waitcnt lgkmcnt(0)" ::: "memory");                          \
    __builtin_amdgcn_s_barrier();                                               \
  } while (0)

// ---------------- GEMM 1: block-Toeplitz conv, 256x256 tile, 8-phase ----------------
// grid 768 = 8 XCD-pinned x {4 channels x 3 coltiles x 8 rowtiles}; big-K (rt=7) first.
// A[row][k] = phi_c[l - k]: Toeplitz staging from Tmat; dlag=-1 -> zero block 512.
// K per block = 256*(rt+1); NITER = 2*(rt+1).

#define STA1(SBUF, SKS, SKT) do { int kt_ = (SKT); if (kt_ < nT) {              \
    int kch_ = kt_ * 64 + (SKS) * 32;                                           \
    int kb_ = kch_ >> 7, bo_ = kch_ & 127;                                      \
    int dl_ = 2 * rt - kb_;                                                     \
    const short* g0_ = (dl_ >= 0) ? (Tc + ((size_t)dl_ << 14) + bo_)            \
                                  : (Tz + bo_);                                 \
    const short* g1_ = Tc + ((size_t)(dl_ + 1) << 14) + bo_;                    \
    gload16(g0_, &As[SBUF][SKS][0][t8]);                                        \
    gload16(g1_, &As[SBUF][SKS][1][t8]); } } while (0)

#define STB1(SBUF, SKS, SKT) do { int kt_ = (SKT); if (kt_ < nT) {              \
    const short* g_ = Bb + kt_ * 64 + (SKS) * 32;                               \
    gload16(g_, &Bs[SBUF][SKS][0][t8]);                                         \
    gload16(g_ + (size_t)128 * SL, &Bs[SBUF][SKS][1][t8]); } } while (0)

__global__ __launch_bounds__(512, 2) void k_gemm1_8p(const short* __restrict__ Tmat,
                                                     const short* __restrict__ xT,
                                                     short* __restrict__ U) {
  __shared__ __align__(16) short As[2][2][2][4096];
  __shared__ __align__(16) short Bs[2][2][2][4096];
  const int bid = blockIdx.x;
  const int xcd = bid & 7;
  const int slot = bid >> 3;                 // 0..95
  const int c = xcd * 4 + (slot & 3);        // 4 channels per XCD (Tmat L2-resident)
  const int q = slot >> 2;                   // 0..23
  const int ct = q % 3;
  const int rt = 7 - q / 3;                  // big K first
  const int nT = 4 * (rt + 1);
  const int nIter = 2 * (rt + 1);
  const int nIterM1 = nIter - 1;
  const int t = threadIdx.x;
  const int lane = t & 63, wave = t >> 6;
  const int wm1 = wave >> 2;
  const int hB = (wave & 3) >> 1;
  const int rB0 = (wave & 1) * 64;
  const int lrow = lane & 15, quad = lane >> 4;
  const int foff = (quad ^ ((lrow >> 1) & 3)) << 3;
  const int r = t >> 2;
  const int cswz = ((t & 3) ^ ((r >> 1) & 3)) << 3;
  const int t8 = t * 8;

  const short* Tc = Tmat + ((size_t)(c * 16) << 14) + r * 128 + cswz;
  const short* Tz = Tmat + ((size_t)512 << 14) + r * 128 + cswz;
  const short* Bb = xT + (size_t)(ct * 256 + r) * SL + cswz;

  f32x4 acc[8][4] = {};

  STB1(0, 0, 0); STA1(0, 0, 0); STB1(0, 1, 0); STA1(0, 1, 0);
  STB1(1, 0, 1); STA1(1, 0, 1); STB1(1, 1, 1);

  for (int j = 0; j < nIter; ++j) {
    bf16x8 bf_[4];
    PHASE(0, 0, 0, 1, STA1(1, 1, 2 * j + 1));
    PHASE(0, 0, 1, 0, STB1(0, 0, 2 * j + 2));
    PHASE(0, 1, 0, 0, STA1(0, 0, 2 * j + 2));
    PHASE(0, 1, 1, 0, STB1(0, 1, 2 * j + 2));
    PHASE(1, 0, 0, 2, STA1(0, 1, 2 * j + 2));
    PHASE(1, 0, 1, 0, STB1(1, 0, 2 * j + 3));
    PHASE(1, 1, 0, 0, STA1(1, 0, 2 * j + 3));
    PHASE(1, 1, 1, 0, STB1(1, 1, 2 * j + 3));
  }

  const int wm128 = (wave >> 2) * 128, wn64 = (wave & 3) * 64;
  const int l0 = rt * 256, colbase = c * DM + ct * 256;
#pragma unroll
  for (int im = 0; im < 8; ++im)
#pragma unroll
    for (int in = 0; in < 4; ++in)
#pragma unroll
      for (int r4 = 0; r4 < 4; ++r4) {
        int row = l0 + wm128 + im * 16 + quad * 4 + r4;
        int col = colbase + wn64 + in * 16 + lrow;
        U[(size_t)row * MTOT + col] = f2bf(acc[im][in][r4]);
      }
}

// ---------------- GEMM 2: 256x256 tile, 8-phase; partial-store epilogue ----------------
// grid 240 = 24 output tiles x SPLITK=10. If use_part: write f32 partials (reduced by
// k_reduce); else atomicAdd fallback (workspace too small).

#define STA2(SBUF, SKS, SKT) do { int kt_ = (SKT); if (kt_ < NT2) {             \
    const short* g_ = Abase + kt_ * 64 + (SKS) * 32;                            \
    gload16(g_, &As[SBUF][SKS][0][t8]);                                         \
    gload16(g_ + (size_t)128 * MTOT, &As[SBUF][SKS][1][t8]); } } while (0)

#define STB2(SBUF, SKS, SKT) do { int kt_ = (SKT); if (kt_ < NT2) {             \
    const short* g_ = Bbase + kt_ * 64 + (SKS) * 32;                            \
    gload16(g_, &Bs[SBUF][SKS][0][t8]);                                         \
    gload16(g_ + (size_t)128 * MTOT, &Bs[SBUF][SKS][1][t8]); } } while (0)

__global__ __launch_bounds__(512, 2) void k_gemm2_8p(const short* __restrict__ U,
                                                     const short* __restrict__ McatT,
                                                     float* __restrict__ out,
                                                     float* __restrict__ part,
                                                     int use_part) {
  __shared__ __align__(16) short As[2][2][2][4096];
  __shared__ __align__(16) short Bs[2][2][2][4096];
  const int bid = blockIdx.x;
  const int tile = bid % 24, kc = bid / 24;
  const int mt = tile & 7, nt_ = tile >> 3;
  const int m0 = mt * 256, o0 = nt_ * 256;
  const int kbase = kc * KSLICE;
  const int t = threadIdx.x;
  const int lane = t & 63, wave = t >> 6;
  const int wm1 = wave >> 2;
  const int hB = (wave & 3) >> 1;
  const int rB0 = (wave & 1) * 64;
  const int lrow = lane & 15, quad = lane >> 4;
  const int foff = (quad ^ ((lrow >> 1) & 3)) << 3;
  const int r = t >> 2;
  const int cswz = ((t & 3) ^ ((r >> 1) & 3)) << 3;
  const int t8 = t * 8;
  const int nIterM1 = NITER2 - 1;

  const short* Abase = U     + (size_t)(m0 + r) * MTOT + kbase + cswz;
  const short* Bbase = McatT + (size_t)(o0 + r) * MTOT + kbase + cswz;

  f32x4 acc[8][4] = {};

  STB2(0, 0, 0); STA2(0, 0, 0); STB2(0, 1, 0); STA2(0, 1, 0);
  STB2(1, 0, 1); STA2(1, 0, 1); STB2(1, 1, 1);

  for (int j = 0; j < NITER2; ++j) {
    bf16x8 bf_[4];
    PHASE(0, 0, 0, 1, STA2(1, 1, 2 * j + 1));
    PHASE(0, 0, 1, 0, STB2(0, 0, 2 * j + 2));
    PHASE(0, 1, 0, 0, STA2(0, 0, 2 * j + 2));
    PHASE(0, 1, 1, 0, STB2(0, 1, 2 * j + 2));
    PHASE(1, 0, 0, 2, STA2(0, 1, 2 * j + 2));
    PHASE(1, 0, 1, 0, STB2(1, 0, 2 * j + 3));
    PHASE(1, 1, 0, 0, STA2(1, 0, 2 * j + 3));
    PHASE(1, 1, 1, 0, STB2(1, 1, 2 * j + 3));
  }

  const int wm128 = (wave >> 2) * 128, wn64 = (wave & 3) * 64;
  if (use_part) {
    float* dst = part + (size_t)kc * (2048 * 768);
#pragma unroll
    for (int im = 0; im < 8; ++im)
#pragma unroll
      for (int in = 0; in < 4; ++in)
#pragma unroll
        for (int r4 = 0; r4 < 4; ++r4) {
          int row = m0 + wm128 + im * 16 + quad * 4 + r4;
          int col = o0 + wn64 + in * 16 + lrow;
          dst[(size_t)row * DM + col] = acc[im][in][r4];
        }
  } else {
#pragma unroll
    for (int im = 0; im < 8; ++im)
#pragma unroll
      for (int in = 0; in < 4; ++in)
#pragma unroll
        for (int r4 = 0; r4 < 4; ++r4) {
          int row = m0 + wm128 + im * 16 + quad * 4 + r4;
          int col = o0 + wn64 + in * 16 + lrow;
          atomicAdd(&out[(size_t)row * DM + col], acc[im][in][r4]);
        }
  }
}

// out = sum over SPLITK partials; one float4 per thread (393216 total)
__global__ __launch_bounds__(256) void k_reduce(const float4* __restrict__ part,
                                                float4* __restrict__ out) {
  int i = blockIdx.x * 256 + threadIdx.x;
  float4 s = part[i];
#pragma unroll
  for (int k = 1; k < SPLITK; ++k) {
    float4 v = part[(size_t)k * 393216 + i];
    s.x += v.x; s.y += v.y; s.z += v.z; s.w += v.w;
  }
  out[i] = s;
}

extern "C" void kernel_launch(void* const* d_in, const int* in_sizes, int n_in,
                              void* d_out, int out_size, void* d_ws, size_t ws_size,
                              hipStream_t stream) {
  (void)in_sizes; (void)n_in; (void)out_size;
  const float* x     = (const float*)d_in[0];
  const float* phi   = (const float*)d_in[1];
  const float* sigma = (const float*)d_in[2];
  const float* Mp    = (const float*)d_in[3];
  const float* Mm    = (const float*)d_in[4];
  const float* Mu    = (const float*)d_in[5];
  float* out = (float*)d_out;
  char* ws = (char*)d_ws;

  short* U     = (short*)(ws + WS_U);
  short* Tmat  = (short*)(ws + WS_TMAT);
  short* xT    = (short*)(ws + WS_XT);
  short* McatT = (short*)(ws + WS_MCAT);
  float* Wpart = (float*)(ws + WS_PART);
  const int use_part = ws_size >= WS_NEED ? 1 : 0;

  if (!use_part)
    k_zero<<<dim3(1536), dim3(256), 0, stream>>>((float4*)out);
  k_prep_all<<<dim3(NB_ALL), dim3(256), 0, stream>>>(x, phi, sigma, Mp, Mm, Mu,
                                                     xT, U, Tmat, McatT);
  k_gemm1_8p<<<dim3(768), dim3(512), 0, stream>>>(Tmat, xT, U);
  k_gemm2_8p<<<dim3(240), dim3(512), 0, stream>>>(U, McatT, out, Wpart, use_part);
  if (use_part)
    k_reduce<<<dim3(1536), dim3(256), 0, stream>>>((const float4*)Wpart, (float4*)out);
}